// Round 7
// baseline (458.583 us; speedup 1.0000x reference)
//
#include <hip/hip_runtime.h>

#define NEG_SLOPE 0.2f
#define BN_EPS 1e-5f

typedef unsigned short u16;
typedef unsigned int u32;
typedef __bf16 bf16x8 __attribute__((ext_vector_type(8)));
typedef float f32x4 __attribute__((ext_vector_type(4)));

__device__ __forceinline__ u32 f2bf(float f) {
    u32 u = __float_as_uint(f);
    return (u + 0x7FFFu + ((u >> 16) & 1u)) >> 16;
}
__device__ __forceinline__ float bf2f(u32 h) { return __uint_as_float(h << 16); }
__device__ __forceinline__ float bfl(u32 p) { return __uint_as_float(p << 16); }
__device__ __forceinline__ float bfh(u32 p) { return __uint_as_float(p & 0xFFFF0000u); }

// ========== split fp32 -> (hi, lo) bf16 pair, 4 elems/thread ==========
__global__ void split_kernel(const float4* __restrict__ X, uint2* __restrict__ hi,
                             uint2* __restrict__ lo, int n4) {
    int i = blockIdx.x * blockDim.x + threadIdx.x;
    if (i >= n4) return;
    float4 v = X[i];
    u32 h0 = f2bf(v.x), h1 = f2bf(v.y), h2 = f2bf(v.z), h3 = f2bf(v.w);
    hi[i] = make_uint2(h0 | (h1 << 16), h2 | (h3 << 16));
    u32 l0 = f2bf(v.x - bf2f(h0)), l1 = f2bf(v.y - bf2f(h1)),
        l2 = f2bf(v.z - bf2f(h2)), l3 = f2bf(v.w - bf2f(h3));
    lo[i] = make_uint2(l0 | (l1 << 16), l2 | (l3 << 16));
}

// ========== weight prep: W[K][N] fp32 -> Wt hi/lo bf16 [N][K] ==========
__global__ void wt_prep(const float* __restrict__ W, u16* __restrict__ hi,
                        u16* __restrict__ lo, int K, int N) {
    int i = blockIdx.x * blockDim.x + threadIdx.x;
    if (i >= K * N) return;
    int k = i / N, n = i - k * N;
    float w = W[i];
    u32 h = f2bf(w);
    hi[n * K + k] = (u16)h;
    lo[n * K + k] = (u16)f2bf(w - bf2f(h));
}

// ========== split-bf16 MFMA GEMM -> bf16 output ==========
// A as Ahi/Alo bf16 [M][K]; B as Bhi/Blo bf16 [N][K] (transposed).
// BN=128: 4 waves 2x2, 64x64/wave. BN=64: 4 waves 4x1, 32x64/wave.
template<int BN>
__launch_bounds__(256)
__global__ void gemm_mfma(const u16* __restrict__ Ahi, const u16* __restrict__ Alo,
                          const u16* __restrict__ Bhi, const u16* __restrict__ Blo,
                          u16* __restrict__ Cbf, int M, int K, int N) {
    constexpr int FM = (BN == 128) ? 4 : 2;
    __shared__ uint4 sA[2][512];
    __shared__ uint4 sB[2][BN * 4];
    const int tid = threadIdx.x;
    const int bm = blockIdx.y * 128;
    const int bn = blockIdx.x * BN;
    const int lane = tid & 63;
    const int w = tid >> 6;
    const int wm = (BN == 128) ? (w >> 1) * 64 : w * 32;
    const int wn = (BN == 128) ? (w & 1) * 64 : 0;
    const int fr = lane & 15;
    const int fs = lane >> 4;
    f32x4 zero = {0.f, 0.f, 0.f, 0.f};
    f32x4 acc[FM][4];
    #pragma unroll
    for (int i = 0; i < FM; i++)
        #pragma unroll
        for (int j = 0; j < 4; j++) acc[i][j] = zero;

    const int r0 = tid >> 2;     // 0..63
    const int ss = tid & 3;
    const int r1 = r0 + 64;
    const int d0 = r0 * 4 + (ss ^ ((r0 >> 1) & 3));
    const int d1 = r1 * 4 + (ss ^ ((r1 >> 1) & 3));

    for (int k0 = 0; k0 < K; k0 += 32) {
        {   // A tile: 128 rows
            int gr = bm + r0;
            uint4 vh = make_uint4(0, 0, 0, 0), vl = make_uint4(0, 0, 0, 0);
            if (gr < M) {
                vh = *(const uint4*)(Ahi + (size_t)gr * K + k0 + ss * 8);
                vl = *(const uint4*)(Alo + (size_t)gr * K + k0 + ss * 8);
            }
            sA[0][d0] = vh; sA[1][d0] = vl;
            gr = bm + r1;
            vh = make_uint4(0, 0, 0, 0); vl = make_uint4(0, 0, 0, 0);
            if (gr < M) {
                vh = *(const uint4*)(Ahi + (size_t)gr * K + k0 + ss * 8);
                vl = *(const uint4*)(Alo + (size_t)gr * K + k0 + ss * 8);
            }
            sA[0][d1] = vh; sA[1][d1] = vl;
        }
        {   // B tile: BN rows
            int gr = bn + r0;
            sB[0][d0] = *(const uint4*)(Bhi + (size_t)gr * K + k0 + ss * 8);
            sB[1][d0] = *(const uint4*)(Blo + (size_t)gr * K + k0 + ss * 8);
            if constexpr (BN == 128) {
                gr = bn + r1;
                sB[0][d1] = *(const uint4*)(Bhi + (size_t)gr * K + k0 + ss * 8);
                sB[1][d1] = *(const uint4*)(Blo + (size_t)gr * K + k0 + ss * 8);
            }
        }
        __syncthreads();
        bf16x8 ah[FM], al[FM], bh[4], bl[4];
        #pragma unroll
        for (int mi = 0; mi < FM; mi++) {
            int row = wm + mi * 16 + fr;
            int idx = row * 4 + (fs ^ ((row >> 1) & 3));
            ah[mi] = *reinterpret_cast<const bf16x8*>(&sA[0][idx]);
            al[mi] = *reinterpret_cast<const bf16x8*>(&sA[1][idx]);
        }
        #pragma unroll
        for (int ni = 0; ni < 4; ni++) {
            int row = wn + ni * 16 + fr;
            int idx = row * 4 + (fs ^ ((row >> 1) & 3));
            bh[ni] = *reinterpret_cast<const bf16x8*>(&sB[0][idx]);
            bl[ni] = *reinterpret_cast<const bf16x8*>(&sB[1][idx]);
        }
        #pragma unroll
        for (int mi = 0; mi < FM; mi++)
            #pragma unroll
            for (int ni = 0; ni < 4; ni++) {
                acc[mi][ni] = __builtin_amdgcn_mfma_f32_16x16x32_bf16(ah[mi], bh[ni], acc[mi][ni], 0, 0, 0);
                acc[mi][ni] = __builtin_amdgcn_mfma_f32_16x16x32_bf16(ah[mi], bl[ni], acc[mi][ni], 0, 0, 0);
                acc[mi][ni] = __builtin_amdgcn_mfma_f32_16x16x32_bf16(al[mi], bh[ni], acc[mi][ni], 0, 0, 0);
            }
        __syncthreads();
    }
    // C/D layout: col = lane&15, row = (lane>>4)*4 + reg
    #pragma unroll
    for (int mi = 0; mi < FM; mi++) {
        #pragma unroll
        for (int ni = 0; ni < 4; ni++) {
            int colg = bn + wn + ni * 16 + fr;
            int rbase = bm + wm + mi * 16 + fs * 4;
            #pragma unroll
            for (int r = 0; r < 4; r++) {
                int rw = rbase + r;
                if (rw < M) Cbf[(size_t)rw * N + colg] = (u16)f2bf(acc[mi][ni][r]);
            }
        }
    }
}

// ================= small GEMM for layer 4: K=64, N=16 -> bf16 out =================
__launch_bounds__(256)
__global__ void gemm_k64n16(const float* __restrict__ A, const float* __restrict__ B,
                            u16* __restrict__ Cbf, int M) {
    __shared__ float As[64][68];
    __shared__ float Bs[64][16];
    const int tid = threadIdx.x;
    const int bm = blockIdx.x * 64;
    {
        int r = tid >> 2, c = (tid & 3) << 2;
        *reinterpret_cast<float4*>(&Bs[r][c]) = *reinterpret_cast<const float4*>(&B[r * 16 + c]);
    }
    #pragma unroll
    for (int p = 0; p < 4; p++) {
        int m = (tid >> 4) + p * 16;
        int c = (tid & 15) << 2;
        int gm = bm + m;
        float4 v = make_float4(0.f, 0.f, 0.f, 0.f);
        if (gm < M) v = *reinterpret_cast<const float4*>(&A[(size_t)gm * 64 + c]);
        *reinterpret_cast<float4*>(&As[m][c]) = v;
    }
    __syncthreads();
    const int tc = tid & 15;
    const int r0 = tid >> 4;
    float acc[4] = {};
    #pragma unroll
    for (int k4 = 0; k4 < 16; k4++) {
        float b0 = Bs[4 * k4 + 0][tc];
        float b1 = Bs[4 * k4 + 1][tc];
        float b2 = Bs[4 * k4 + 2][tc];
        float b3 = Bs[4 * k4 + 3][tc];
        #pragma unroll
        for (int i = 0; i < 4; i++) {
            float4 av = *reinterpret_cast<const float4*>(&As[r0 + i * 16][4 * k4]);
            acc[i] += av.x * b0 + av.y * b1 + av.z * b2 + av.w * b3;
        }
    }
    #pragma unroll
    for (int i = 0; i < 4; i++) {
        int m = bm + r0 + i * 16;
        if (m < M) Cbf[(size_t)m * 16 + tc] = (u16)f2bf(acc[i]);
    }
}

// ================= per-node attention scores (bf16 h) =================
__global__ void scores_kernel(const u16* __restrict__ h,
                              const float* __restrict__ asrc,
                              const float* __restrict__ adst,
                              float* __restrict__ es, float* __restrict__ ed,
                              int Nn, int H, int C) {
    int idx = blockIdx.x * blockDim.x + threadIdx.x;
    if (idx >= Nn * H) return;
    int n = idx / H, hh = idx % H;
    const u16* hp = h + ((size_t)n * H + hh) * C;
    const float4* ap = reinterpret_cast<const float4*>(asrc + hh * C);
    const float4* bp = reinterpret_cast<const float4*>(adst + hh * C);
    float s = 0.f, d = 0.f;
    for (int c4 = 0; c4 < C / 4; c4++) {
        uint2 pv = *reinterpret_cast<const uint2*>(hp + 4 * c4);
        float v0 = bfl(pv.x), v1 = bfh(pv.x), v2 = bfl(pv.y), v3 = bfh(pv.y);
        float4 a = ap[c4], b = bp[c4];
        s += v0 * a.x + v1 * a.y + v2 * a.z + v3 * a.w;
        d += v0 * b.x + v1 * b.y + v2 * b.z + v3 * b.w;
    }
    es[idx] = s;
    ed[idx] = d;
}

// ================= CSR build =================
__global__ void hist_kernel(const int* __restrict__ dst, int* __restrict__ counts,
                            int E0, int Etot) {
    int e = blockIdx.x * blockDim.x + threadIdx.x;
    if (e >= Etot) return;
    int d_ = (e < E0) ? dst[e] : e - E0;
    atomicAdd(&counts[d_], 1);
}

__global__ void scan_kernel(const int* __restrict__ counts, int* __restrict__ row_ptr, int Nn) {
    __shared__ int wsum[16];
    __shared__ int chunk_total;
    __shared__ int carry_s;
    const int tid = threadIdx.x;
    const int lane = tid & 63;
    const int wid = tid >> 6;
    if (tid == 0) carry_s = 0;
    __syncthreads();
    for (int base = 0; base < Nn; base += 1024) {
        int i = base + tid;
        int v = (i < Nn) ? counts[i] : 0;
        int iv = v;
        #pragma unroll
        for (int off = 1; off < 64; off <<= 1) {
            int t = __shfl_up(iv, off, 64);
            if (lane >= off) iv += t;
        }
        if (lane == 63) wsum[wid] = iv;
        __syncthreads();
        if (tid == 0) {
            int s = 0;
            #pragma unroll
            for (int k = 0; k < 16; k++) { int t = wsum[k]; wsum[k] = s; s += t; }
            chunk_total = s;
        }
        __syncthreads();
        if (i < Nn) row_ptr[i] = carry_s + wsum[wid] + (iv - v);
        __syncthreads();
        if (tid == 0) carry_s += chunk_total;
        __syncthreads();
    }
    if (tid == 0) row_ptr[Nn] = carry_s;
}

__global__ void scatter_kernel(const int* __restrict__ src, const int* __restrict__ dst,
                               int* __restrict__ cursor, int* __restrict__ col,
                               int E0, int Etot) {
    int e = blockIdx.x * blockDim.x + threadIdx.x;
    if (e >= Etot) return;
    int d_ = (e < E0) ? dst[e] : e - E0;
    int s_ = (e < E0) ? src[e] : e - E0;
    int pos = atomicAdd(&cursor[d_], 1);
    col[pos] = s_;
}

// ========== fused softmax + aggregate + bias + ELU + BN, barrier-free (wave-private LDS) ==========
// NT threads per node, NT <= 64 and node-group never spans a wave boundary.
template<int H, int C, int NT, int DO_ELU, int OUT_HILO>
__launch_bounds__(256)
__global__ void gat_fused(const int* __restrict__ row_ptr, const int* __restrict__ col,
                          const float* __restrict__ es, const float* __restrict__ ed,
                          const u16* __restrict__ h16, float* __restrict__ outf,
                          u16* __restrict__ outh, u16* __restrict__ outl,
                          const float* __restrict__ bias, const float* __restrict__ g,
                          const float* __restrict__ be, const float* __restrict__ rm,
                          const float* __restrict__ rv, int Nn) {
    constexpr int Dout = H * C;
    constexpr int VEC = Dout / NT;
    constexpr int NPB = 256 / NT;
    constexpr int CH = 32;
    __shared__ float w_s[NPB][CH][H];
    __shared__ int   c_s[NPB][CH];
    const int tid = threadIdx.x;
    const int slot = tid / NT;
    const int t = tid % NT;
    const int node = blockIdx.x * NPB + slot;
    if (node >= Nn) return;
    const int jb = row_ptr[node], je = row_ptr[node + 1];
    float edv[H];
    if constexpr (H == 8) {
        float4 e0 = *reinterpret_cast<const float4*>(&ed[node * 8]);
        float4 e1 = *reinterpret_cast<const float4*>(&ed[node * 8 + 4]);
        edv[0] = e0.x; edv[1] = e0.y; edv[2] = e0.z; edv[3] = e0.w;
        edv[4] = e1.x; edv[5] = e1.y; edv[6] = e1.z; edv[7] = e1.w;
    } else {
        edv[0] = ed[node];
    }
    const int c0 = t * VEC;
    const int hh = c0 / C;
    float acc[VEC] = {};
    float den = 0.f;
    for (int j0 = jb; j0 < je; j0 += CH) {
        int cnt = je - j0;
        if (cnt > CH) cnt = CH;
        for (int tt = t; tt < cnt; tt += NT) {
            int s = col[j0 + tt];
            c_s[slot][tt] = s;
            if constexpr (H == 8) {
                float4 q0 = *reinterpret_cast<const float4*>(&es[s * 8]);
                float4 q1 = *reinterpret_cast<const float4*>(&es[s * 8 + 4]);
                float al8[8] = {q0.x, q0.y, q0.z, q0.w, q1.x, q1.y, q1.z, q1.w};
                #pragma unroll
                for (int h2 = 0; h2 < 8; h2++) {
                    float a = al8[h2] + edv[h2];
                    a = (a >= 0.f) ? a : NEG_SLOPE * a;
                    w_s[slot][tt][h2] = __expf(a);
                }
            } else {
                float a = es[s] + edv[0];
                a = (a >= 0.f) ? a : NEG_SLOPE * a;
                w_s[slot][tt][0] = __expf(a);
            }
        }
        // wave-local: group's LDS writes visible after lgkmcnt(0); no block barrier needed
        asm volatile("s_waitcnt lgkmcnt(0)" ::: "memory");
        int j = 0;
        for (; j + 4 <= cnt; j += 4) {
            int sx[4]; float ww[4];
            #pragma unroll
            for (int u = 0; u < 4; u++) { sx[u] = c_s[slot][j + u]; ww[u] = w_s[slot][j + u][hh]; }
            if constexpr (VEC == 8) {
                uint4 pv[4];
                #pragma unroll
                for (int u = 0; u < 4; u++)
                    pv[u] = *reinterpret_cast<const uint4*>(h16 + (size_t)sx[u] * Dout + c0);
                #pragma unroll
                for (int u = 0; u < 4; u++) {
                    den += ww[u];
                    acc[0] += ww[u] * bfl(pv[u].x); acc[1] += ww[u] * bfh(pv[u].x);
                    acc[2] += ww[u] * bfl(pv[u].y); acc[3] += ww[u] * bfh(pv[u].y);
                    acc[4] += ww[u] * bfl(pv[u].z); acc[5] += ww[u] * bfh(pv[u].z);
                    acc[6] += ww[u] * bfl(pv[u].w); acc[7] += ww[u] * bfh(pv[u].w);
                }
            } else {    // VEC == 4
                uint2 pv[4];
                #pragma unroll
                for (int u = 0; u < 4; u++)
                    pv[u] = *reinterpret_cast<const uint2*>(h16 + (size_t)sx[u] * Dout + c0);
                #pragma unroll
                for (int u = 0; u < 4; u++) {
                    den += ww[u];
                    acc[0] += ww[u] * bfl(pv[u].x); acc[1] += ww[u] * bfh(pv[u].x);
                    acc[2] += ww[u] * bfl(pv[u].y); acc[3] += ww[u] * bfh(pv[u].y);
                }
            }
        }
        for (; j < cnt; j++) {
            float w = w_s[slot][j][hh];
            den += w;
            const u16* hp = h16 + (size_t)c_s[slot][j] * Dout + c0;
            if constexpr (VEC == 8) {
                uint4 pv = *reinterpret_cast<const uint4*>(hp);
                acc[0] += w * bfl(pv.x); acc[1] += w * bfh(pv.x);
                acc[2] += w * bfl(pv.y); acc[3] += w * bfh(pv.y);
                acc[4] += w * bfl(pv.z); acc[5] += w * bfh(pv.z);
                acc[6] += w * bfl(pv.w); acc[7] += w * bfh(pv.w);
            } else {
                uint2 pv = *reinterpret_cast<const uint2*>(hp);
                acc[0] += w * bfl(pv.x); acc[1] += w * bfh(pv.x);
                acc[2] += w * bfl(pv.y); acc[3] += w * bfh(pv.y);
            }
        }
        // WAR guard: reads drained before next chunk overwrites the slot
        asm volatile("s_waitcnt lgkmcnt(0)" ::: "memory");
    }
    const float inv = 1.f / (den + 1e-16f);
    float res[VEC];
    #pragma unroll
    for (int v = 0; v < VEC; v++) {
        const int jc = c0 + v;
        float y = acc[v] * inv + bias[jc];
        if (DO_ELU) y = (y > 0.f) ? y : expm1f(y);
        y = (y - rm[jc]) * rsqrtf(rv[jc] + BN_EPS) * g[jc] + be[jc];
        res[v] = y;
    }
    if constexpr (OUT_HILO) {
        u32 rh[VEC], rl[VEC];
        #pragma unroll
        for (int v = 0; v < VEC; v++) {
            rh[v] = f2bf(res[v]);
            rl[v] = f2bf(res[v] - bf2f(rh[v]));
        }
        if constexpr (VEC == 8) {
            uint4 ph = make_uint4(rh[0] | (rh[1] << 16), rh[2] | (rh[3] << 16),
                                  rh[4] | (rh[5] << 16), rh[6] | (rh[7] << 16));
            uint4 pl = make_uint4(rl[0] | (rl[1] << 16), rl[2] | (rl[3] << 16),
                                  rl[4] | (rl[5] << 16), rl[6] | (rl[7] << 16));
            *reinterpret_cast<uint4*>(outh + (size_t)node * Dout + c0) = ph;
            *reinterpret_cast<uint4*>(outl + (size_t)node * Dout + c0) = pl;
        } else {
            uint2 ph = make_uint2(rh[0] | (rh[1] << 16), rh[2] | (rh[3] << 16));
            uint2 pl = make_uint2(rl[0] | (rl[1] << 16), rl[2] | (rl[3] << 16));
            *reinterpret_cast<uint2*>(outh + (size_t)node * Dout + c0) = ph;
            *reinterpret_cast<uint2*>(outl + (size_t)node * Dout + c0) = pl;
        }
    } else {
        float* op = outf + (size_t)node * Dout + c0;
        if constexpr (VEC == 8) {
            *reinterpret_cast<float4*>(op) = make_float4(res[0], res[1], res[2], res[3]);
            *reinterpret_cast<float4*>(op + 4) = make_float4(res[4], res[5], res[6], res[7]);
        } else {
            *reinterpret_cast<float4*>(op) = make_float4(res[0], res[1], res[2], res[3]);
        }
    }
}

extern "C" void kernel_launch(void* const* d_in, const int* in_sizes, int n_in,
                              void* d_out, int out_size, void* d_ws, size_t ws_size,
                              hipStream_t stream) {
    const float* x = (const float*)d_in[0];
    const int* src = (const int*)d_in[1];
    const int* dst = (const int*)d_in[2];
    const int Nn = in_sizes[0] / 128;   // 50000
    const int E0 = in_sizes[1];         // 400000
    const int Etot = E0 + Nn;

    // ---- workspace layout (~108 MB) ----
    u16* A0 = (u16*)d_ws;                                  // region A: Nn*512 u16 (51.2MB)
    u16* Bh = A0 + (size_t)Nn * 512;                       // region B: Nn*256 u16 (25.6MB) - GEMM bf16 out
    u16* Ch = Bh + (size_t)Nn * 256;                       // region C: Nn*256 u16 (25.6MB) - Y2 hi/lo
    float* es = (float*)(Ch + (size_t)Nn * 256);           // Nn*8
    float* ed = es + (size_t)Nn * 8;                       // Nn*8
    int* row_ptr = (int*)(ed + (size_t)Nn * 8);            // Nn+1
    int* cursor  = row_ptr + (Nn + 1);                     // Nn
    int* col     = cursor + Nn;                            // Etot
    u16* wth = (u16*)(col + Etot);                         // 64K u16
    u16* wtl = wth + 65536;

    // region A sub-views
    u16* XH = A0;                          // Nn*128 (layer-1 input hi)
    u16* XL = A0 + (size_t)Nn * 128;       // Nn*128 (lo)
    u16* Y1H = A0;                         // Nn*256 (layer-1 output hi; overwrites dead X)
    u16* Y1L = A0 + (size_t)Nn * 256;      // Nn*256
    u16* Y2H = Ch;                         // Nn*128
    u16* Y2L = Ch + (size_t)Nn * 128;      // Nn*128
    float* out3 = (float*)A0;              // Nn*64 fp32 (overwrites dead Y1)

    // ---- CSR build ----
    hipMemsetAsync(cursor, 0, sizeof(int) * Nn, stream);
    hist_kernel<<<(Etot + 255) / 256, 256, 0, stream>>>(dst, cursor, E0, Etot);
    scan_kernel<<<1, 1024, 0, stream>>>(cursor, row_ptr, Nn);
    hipMemcpyAsync(cursor, row_ptr, sizeof(int) * Nn, hipMemcpyDeviceToDevice, stream);
    scatter_kernel<<<(Etot + 255) / 256, 256, 0, stream>>>(src, dst, cursor, col, E0, Etot);

    const int gy128 = (Nn + 127) / 128;

    for (int l = 0; l < 4; l++) {
        const float* const* p = (const float* const*)(d_in + 3 + l * 8);
        const float* W    = p[0];
        const float* asrc = p[1];
        const float* adst = p[2];
        const float* bias = p[3];
        const float* g    = p[4];
        const float* be   = p[5];
        const float* rm   = p[6];
        const float* rv   = p[7];

        if (l == 0) {
            const int K = 128, N = 256;
            int n4 = Nn * K / 4;
            split_kernel<<<(n4 + 255) / 256, 256, 0, stream>>>(
                (const float4*)x, (uint2*)XH, (uint2*)XL, n4);
            wt_prep<<<(K * N + 255) / 256, 256, 0, stream>>>(W, wth, wtl, K, N);
            gemm_mfma<128><<<dim3(N / 128, gy128), 256, 0, stream>>>(XH, XL, wth, wtl, Bh, Nn, K, N);
            scores_kernel<<<(Nn * 8 + 255) / 256, 256, 0, stream>>>(Bh, asrc, adst, es, ed, Nn, 8, 32);
            gat_fused<8, 32, 32, 1, 1><<<(Nn + 7) / 8, 256, 0, stream>>>(
                row_ptr, col, es, ed, Bh, nullptr, Y1H, Y1L, bias, g, be, rm, rv, Nn);
        } else if (l == 1) {
            const int K = 256, N = 128;
            wt_prep<<<(K * N + 255) / 256, 256, 0, stream>>>(W, wth, wtl, K, N);
            gemm_mfma<128><<<dim3(1, gy128), 256, 0, stream>>>(Y1H, Y1L, wth, wtl, Bh, Nn, K, N);
            scores_kernel<<<(Nn * 8 + 255) / 256, 256, 0, stream>>>(Bh, asrc, adst, es, ed, Nn, 8, 16);
            gat_fused<8, 16, 16, 1, 1><<<(Nn + 15) / 16, 256, 0, stream>>>(
                row_ptr, col, es, ed, Bh, nullptr, Y2H, Y2L, bias, g, be, rm, rv, Nn);
        } else if (l == 2) {
            const int K = 128, N = 64;
            wt_prep<<<(K * N + 255) / 256, 256, 0, stream>>>(W, wth, wtl, K, N);
            gemm_mfma<64><<<dim3(1, gy128), 256, 0, stream>>>(Y2H, Y2L, wth, wtl, Bh, Nn, K, N);
            scores_kernel<<<(Nn * 8 + 255) / 256, 256, 0, stream>>>(Bh, asrc, adst, es, ed, Nn, 8, 8);
            gat_fused<8, 8, 16, 1, 0><<<(Nn + 15) / 16, 256, 0, stream>>>(
                row_ptr, col, es, ed, Bh, out3, nullptr, nullptr, bias, g, be, rm, rv, Nn);
        } else {
            gemm_k64n16<<<(Nn + 63) / 64, 256, 0, stream>>>(out3, W, Bh, Nn);
            scores_kernel<<<(Nn + 255) / 256, 256, 0, stream>>>(Bh, asrc, adst, es, ed, Nn, 1, 16);
            gat_fused<1, 16, 4, 0, 0><<<(Nn + 63) / 64, 256, 0, stream>>>(
                row_ptr, col, es, ed, Bh, (float*)d_out, nullptr, nullptr, bias, g, be, rm, rv, Nn);
        }
    }
}

// Round 8
// 405.332 us; speedup vs baseline: 1.1314x; 1.1314x over previous
//
#include <hip/hip_runtime.h>

#define NEG_SLOPE 0.2f
#define BN_EPS 1e-5f

typedef unsigned short u16;
typedef unsigned int u32;
typedef __bf16 bf16x8 __attribute__((ext_vector_type(8)));
typedef float f32x4 __attribute__((ext_vector_type(4)));

__device__ __forceinline__ u32 f2bf(float f) {
    u32 u = __float_as_uint(f);
    return (u + 0x7FFFu + ((u >> 16) & 1u)) >> 16;
}
__device__ __forceinline__ float bf2f(u32 h) { return __uint_as_float(h << 16); }
__device__ __forceinline__ float bfl(u32 p) { return __uint_as_float(p << 16); }
__device__ __forceinline__ float bfh(u32 p) { return __uint_as_float(p & 0xFFFF0000u); }

// ========== split fp32 -> (hi, lo) bf16 pair, 4 elems/thread ==========
__global__ void split_kernel(const float4* __restrict__ X, uint2* __restrict__ hi,
                             uint2* __restrict__ lo, int n4) {
    int i = blockIdx.x * blockDim.x + threadIdx.x;
    if (i >= n4) return;
    float4 v = X[i];
    u32 h0 = f2bf(v.x), h1 = f2bf(v.y), h2 = f2bf(v.z), h3 = f2bf(v.w);
    hi[i] = make_uint2(h0 | (h1 << 16), h2 | (h3 << 16));
    u32 l0 = f2bf(v.x - bf2f(h0)), l1 = f2bf(v.y - bf2f(h1)),
        l2 = f2bf(v.z - bf2f(h2)), l3 = f2bf(v.w - bf2f(h3));
    lo[i] = make_uint2(l0 | (l1 << 16), l2 | (l3 << 16));
}

// ========== weight prep: W[K][N] fp32 -> Wt hi/lo bf16 [N][K] ==========
__global__ void wt_prep(const float* __restrict__ W, u16* __restrict__ hi,
                        u16* __restrict__ lo, int K, int N) {
    int i = blockIdx.x * blockDim.x + threadIdx.x;
    if (i >= K * N) return;
    int k = i / N, n = i - k * N;
    float w = W[i];
    u32 h = f2bf(w);
    hi[n * K + k] = (u16)h;
    lo[n * K + k] = (u16)f2bf(w - bf2f(h));
}

// ========== split-bf16 MFMA GEMM -> bf16 output (optionally head-major) ==========
// A as Ahi/Alo bf16 [M][K]; B as Bhi/Blo bf16 [N][K] (transposed).
// HMC>0: output written head-major as C[hh][m][HMC] with hh=col/HMC.
template<int BN, int HMC>
__launch_bounds__(256)
__global__ void gemm_mfma(const u16* __restrict__ Ahi, const u16* __restrict__ Alo,
                          const u16* __restrict__ Bhi, const u16* __restrict__ Blo,
                          u16* __restrict__ Cbf, int M, int K, int N) {
    constexpr int FM = (BN == 128) ? 4 : 2;
    __shared__ uint4 sA[2][512];
    __shared__ uint4 sB[2][BN * 4];
    const int tid = threadIdx.x;
    const int bm = blockIdx.y * 128;
    const int bn = blockIdx.x * BN;
    const int lane = tid & 63;
    const int w = tid >> 6;
    const int wm = (BN == 128) ? (w >> 1) * 64 : w * 32;
    const int wn = (BN == 128) ? (w & 1) * 64 : 0;
    const int fr = lane & 15;
    const int fs = lane >> 4;
    f32x4 zero = {0.f, 0.f, 0.f, 0.f};
    f32x4 acc[FM][4];
    #pragma unroll
    for (int i = 0; i < FM; i++)
        #pragma unroll
        for (int j = 0; j < 4; j++) acc[i][j] = zero;

    const int r0 = tid >> 2;
    const int ss = tid & 3;
    const int r1 = r0 + 64;
    const int d0 = r0 * 4 + (ss ^ ((r0 >> 1) & 3));
    const int d1 = r1 * 4 + (ss ^ ((r1 >> 1) & 3));

    for (int k0 = 0; k0 < K; k0 += 32) {
        {
            int gr = bm + r0;
            uint4 vh = make_uint4(0, 0, 0, 0), vl = make_uint4(0, 0, 0, 0);
            if (gr < M) {
                vh = *(const uint4*)(Ahi + (size_t)gr * K + k0 + ss * 8);
                vl = *(const uint4*)(Alo + (size_t)gr * K + k0 + ss * 8);
            }
            sA[0][d0] = vh; sA[1][d0] = vl;
            gr = bm + r1;
            vh = make_uint4(0, 0, 0, 0); vl = make_uint4(0, 0, 0, 0);
            if (gr < M) {
                vh = *(const uint4*)(Ahi + (size_t)gr * K + k0 + ss * 8);
                vl = *(const uint4*)(Alo + (size_t)gr * K + k0 + ss * 8);
            }
            sA[0][d1] = vh; sA[1][d1] = vl;
        }
        {
            int gr = bn + r0;
            sB[0][d0] = *(const uint4*)(Bhi + (size_t)gr * K + k0 + ss * 8);
            sB[1][d0] = *(const uint4*)(Blo + (size_t)gr * K + k0 + ss * 8);
            if constexpr (BN == 128) {
                gr = bn + r1;
                sB[0][d1] = *(const uint4*)(Bhi + (size_t)gr * K + k0 + ss * 8);
                sB[1][d1] = *(const uint4*)(Blo + (size_t)gr * K + k0 + ss * 8);
            }
        }
        __syncthreads();
        bf16x8 ah[FM], al[FM], bh[4], bl[4];
        #pragma unroll
        for (int mi = 0; mi < FM; mi++) {
            int row = wm + mi * 16 + fr;
            int idx = row * 4 + (fs ^ ((row >> 1) & 3));
            ah[mi] = *reinterpret_cast<const bf16x8*>(&sA[0][idx]);
            al[mi] = *reinterpret_cast<const bf16x8*>(&sA[1][idx]);
        }
        #pragma unroll
        for (int ni = 0; ni < 4; ni++) {
            int row = wn + ni * 16 + fr;
            int idx = row * 4 + (fs ^ ((row >> 1) & 3));
            bh[ni] = *reinterpret_cast<const bf16x8*>(&sB[0][idx]);
            bl[ni] = *reinterpret_cast<const bf16x8*>(&sB[1][idx]);
        }
        #pragma unroll
        for (int mi = 0; mi < FM; mi++)
            #pragma unroll
            for (int ni = 0; ni < 4; ni++) {
                acc[mi][ni] = __builtin_amdgcn_mfma_f32_16x16x32_bf16(ah[mi], bh[ni], acc[mi][ni], 0, 0, 0);
                acc[mi][ni] = __builtin_amdgcn_mfma_f32_16x16x32_bf16(ah[mi], bl[ni], acc[mi][ni], 0, 0, 0);
                acc[mi][ni] = __builtin_amdgcn_mfma_f32_16x16x32_bf16(al[mi], bh[ni], acc[mi][ni], 0, 0, 0);
            }
        __syncthreads();
    }
    // C/D layout: col = lane&15, row = (lane>>4)*4 + reg
    #pragma unroll
    for (int mi = 0; mi < FM; mi++) {
        #pragma unroll
        for (int ni = 0; ni < 4; ni++) {
            int colg = bn + wn + ni * 16 + fr;
            int rbase = bm + wm + mi * 16 + fs * 4;
            #pragma unroll
            for (int r = 0; r < 4; r++) {
                int rw = rbase + r;
                if (rw >= M) continue;
                u16 val = (u16)f2bf(acc[mi][ni][r]);
                if constexpr (HMC > 0) {
                    int hh2 = colg / HMC, cc2 = colg - hh2 * HMC;
                    Cbf[((size_t)hh2 * M + rw) * HMC + cc2] = val;
                } else {
                    Cbf[(size_t)rw * N + colg] = val;
                }
            }
        }
    }
}

// ================= small GEMM for layer 4: K=64, N=16 -> bf16 out =================
__launch_bounds__(256)
__global__ void gemm_k64n16(const float* __restrict__ A, const float* __restrict__ B,
                            u16* __restrict__ Cbf, int M) {
    __shared__ float As[64][68];
    __shared__ float Bs[64][16];
    const int tid = threadIdx.x;
    const int bm = blockIdx.x * 64;
    {
        int r = tid >> 2, c = (tid & 3) << 2;
        *reinterpret_cast<float4*>(&Bs[r][c]) = *reinterpret_cast<const float4*>(&B[r * 16 + c]);
    }
    #pragma unroll
    for (int p = 0; p < 4; p++) {
        int m = (tid >> 4) + p * 16;
        int c = (tid & 15) << 2;
        int gm = bm + m;
        float4 v = make_float4(0.f, 0.f, 0.f, 0.f);
        if (gm < M) v = *reinterpret_cast<const float4*>(&A[(size_t)gm * 64 + c]);
        *reinterpret_cast<float4*>(&As[m][c]) = v;
    }
    __syncthreads();
    const int tc = tid & 15;
    const int r0 = tid >> 4;
    float acc[4] = {};
    #pragma unroll
    for (int k4 = 0; k4 < 16; k4++) {
        float b0 = Bs[4 * k4 + 0][tc];
        float b1 = Bs[4 * k4 + 1][tc];
        float b2 = Bs[4 * k4 + 2][tc];
        float b3 = Bs[4 * k4 + 3][tc];
        #pragma unroll
        for (int i = 0; i < 4; i++) {
            float4 av = *reinterpret_cast<const float4*>(&As[r0 + i * 16][4 * k4]);
            acc[i] += av.x * b0 + av.y * b1 + av.z * b2 + av.w * b3;
        }
    }
    #pragma unroll
    for (int i = 0; i < 4; i++) {
        int m = bm + r0 + i * 16;
        if (m < M) Cbf[(size_t)m * 16 + tc] = (u16)f2bf(acc[i]);
    }
}

// ========== per-node attention scores (bf16 head-major h; es/ed head-major) ==========
__global__ void scores_kernel(const u16* __restrict__ h,
                              const float* __restrict__ asrc,
                              const float* __restrict__ adst,
                              float* __restrict__ es, float* __restrict__ ed,
                              int Nn, int H, int C) {
    int idx = blockIdx.x * blockDim.x + threadIdx.x;
    if (idx >= Nn * H) return;
    int n = idx / H, hh = idx % H;
    const u16* hp = h + ((size_t)hh * Nn + n) * C;
    const float4* ap = reinterpret_cast<const float4*>(asrc + hh * C);
    const float4* bp = reinterpret_cast<const float4*>(adst + hh * C);
    float s = 0.f, d = 0.f;
    for (int c4 = 0; c4 < C / 4; c4++) {
        uint2 pv = *reinterpret_cast<const uint2*>(hp + 4 * c4);
        float v0 = bfl(pv.x), v1 = bfh(pv.x), v2 = bfl(pv.y), v3 = bfh(pv.y);
        float4 a = ap[c4], b = bp[c4];
        s += v0 * a.x + v1 * a.y + v2 * a.z + v3 * a.w;
        d += v0 * b.x + v1 * b.y + v2 * b.z + v3 * b.w;
    }
    es[(size_t)hh * Nn + n] = s;
    ed[(size_t)hh * Nn + n] = d;
}

// ================= CSR build =================
__global__ void hist_kernel(const int* __restrict__ dst, int* __restrict__ counts,
                            int E0, int Etot) {
    int e = blockIdx.x * blockDim.x + threadIdx.x;
    if (e >= Etot) return;
    int d_ = (e < E0) ? dst[e] : e - E0;
    atomicAdd(&counts[d_], 1);
}

__global__ void scan_kernel(const int* __restrict__ counts, int* __restrict__ row_ptr, int Nn) {
    __shared__ int wsum[16];
    __shared__ int chunk_total;
    __shared__ int carry_s;
    const int tid = threadIdx.x;
    const int lane = tid & 63;
    const int wid = tid >> 6;
    if (tid == 0) carry_s = 0;
    __syncthreads();
    for (int base = 0; base < Nn; base += 1024) {
        int i = base + tid;
        int v = (i < Nn) ? counts[i] : 0;
        int iv = v;
        #pragma unroll
        for (int off = 1; off < 64; off <<= 1) {
            int t = __shfl_up(iv, off, 64);
            if (lane >= off) iv += t;
        }
        if (lane == 63) wsum[wid] = iv;
        __syncthreads();
        if (tid == 0) {
            int s = 0;
            #pragma unroll
            for (int k = 0; k < 16; k++) { int t = wsum[k]; wsum[k] = s; s += t; }
            chunk_total = s;
        }
        __syncthreads();
        if (i < Nn) row_ptr[i] = carry_s + wsum[wid] + (iv - v);
        __syncthreads();
        if (tid == 0) carry_s += chunk_total;
        __syncthreads();
    }
    if (tid == 0) row_ptr[Nn] = carry_s;
}

__global__ void scatter_kernel(const int* __restrict__ src, const int* __restrict__ dst,
                               int* __restrict__ cursor, int* __restrict__ col,
                               int E0, int Etot) {
    int e = blockIdx.x * blockDim.x + threadIdx.x;
    if (e >= Etot) return;
    int d_ = (e < E0) ? dst[e] : e - E0;
    int s_ = (e < E0) ? src[e] : e - E0;
    int pos = atomicAdd(&cursor[d_], 1);
    col[pos] = s_;
}

// ========== fused softmax + aggregate + bias + ELU + BN ==========
// No LDS, no barriers: NT = C/4 lanes per (node, head) group; col/es loads broadcast
// within the group; exp computed redundantly per lane (cheap); den redundant.
// blockIdx.y = head -> one head's 2*Nn*C bytes fit per-XCD L2.
template<int H, int C, int NT, int DO_ELU, int OUT_HILO>
__launch_bounds__(256)
__global__ void gat_fused(const int* __restrict__ row_ptr, const int* __restrict__ col,
                          const float* __restrict__ es, const float* __restrict__ ed,
                          const u16* __restrict__ h16, float* __restrict__ outf,
                          u16* __restrict__ outh, u16* __restrict__ outl,
                          const float* __restrict__ bias, const float* __restrict__ g,
                          const float* __restrict__ be, const float* __restrict__ rm,
                          const float* __restrict__ rv, int Nn) {
    constexpr int Dout = H * C;
    constexpr int NPB = 256 / NT;        // (node,head) groups per block
    const int tid = threadIdx.x;
    const int node = blockIdx.x * NPB + tid / NT;
    const int t = tid % NT;              // channel lane: c0 = t*4
    const int hh = blockIdx.y;
    if (node >= Nn) return;
    const int jb = row_ptr[node], je = row_ptr[node + 1];
    const float* esh = es + (size_t)hh * Nn;
    const float edv = ed[(size_t)hh * Nn + node];
    const u16* hb = h16 + (size_t)hh * Nn * C + t * 4;
    float a0c = 0.f, a1c = 0.f, a2c = 0.f, a3c = 0.f, den = 0.f;
    int j = jb;
    for (; j + 4 <= je; j += 4) {
        int s0 = col[j], s1 = col[j + 1], s2 = col[j + 2], s3 = col[j + 3];
        float e0 = esh[s0] + edv, e1 = esh[s1] + edv, e2 = esh[s2] + edv, e3 = esh[s3] + edv;
        uint2 p0 = *reinterpret_cast<const uint2*>(hb + (size_t)s0 * C);
        uint2 p1 = *reinterpret_cast<const uint2*>(hb + (size_t)s1 * C);
        uint2 p2 = *reinterpret_cast<const uint2*>(hb + (size_t)s2 * C);
        uint2 p3 = *reinterpret_cast<const uint2*>(hb + (size_t)s3 * C);
        e0 = (e0 >= 0.f) ? e0 : NEG_SLOPE * e0;
        e1 = (e1 >= 0.f) ? e1 : NEG_SLOPE * e1;
        e2 = (e2 >= 0.f) ? e2 : NEG_SLOPE * e2;
        e3 = (e3 >= 0.f) ? e3 : NEG_SLOPE * e3;
        float w0 = __expf(e0), w1 = __expf(e1), w2 = __expf(e2), w3 = __expf(e3);
        den += (w0 + w1) + (w2 + w3);
        a0c += w0 * bfl(p0.x) + w1 * bfl(p1.x) + w2 * bfl(p2.x) + w3 * bfl(p3.x);
        a1c += w0 * bfh(p0.x) + w1 * bfh(p1.x) + w2 * bfh(p2.x) + w3 * bfh(p3.x);
        a2c += w0 * bfl(p0.y) + w1 * bfl(p1.y) + w2 * bfl(p2.y) + w3 * bfl(p3.y);
        a3c += w0 * bfh(p0.y) + w1 * bfh(p1.y) + w2 * bfh(p2.y) + w3 * bfh(p3.y);
    }
    for (; j < je; j++) {
        int s = col[j];
        float a = esh[s] + edv;
        a = (a >= 0.f) ? a : NEG_SLOPE * a;
        float w = __expf(a);
        uint2 pv = *reinterpret_cast<const uint2*>(hb + (size_t)s * C);
        den += w;
        a0c += w * bfl(pv.x); a1c += w * bfh(pv.x);
        a2c += w * bfl(pv.y); a3c += w * bfh(pv.y);
    }
    const float inv = 1.f / (den + 1e-16f);
    const int jc = hh * C + t * 4;
    float res[4] = {a0c, a1c, a2c, a3c};
    #pragma unroll
    for (int v = 0; v < 4; v++) {
        float y = res[v] * inv + bias[jc + v];
        if (DO_ELU) y = (y > 0.f) ? y : expm1f(y);
        y = (y - rm[jc + v]) * rsqrtf(rv[jc + v] + BN_EPS) * g[jc + v] + be[jc + v];
        res[v] = y;
    }
    if constexpr (OUT_HILO) {
        u32 rh[4], rl[4];
        #pragma unroll
        for (int v = 0; v < 4; v++) {
            rh[v] = f2bf(res[v]);
            rl[v] = f2bf(res[v] - bf2f(rh[v]));
        }
        uint2 ph = make_uint2(rh[0] | (rh[1] << 16), rh[2] | (rh[3] << 16));
        uint2 pl = make_uint2(rl[0] | (rl[1] << 16), rl[2] | (rl[3] << 16));
        *reinterpret_cast<uint2*>(outh + (size_t)node * Dout + jc) = ph;
        *reinterpret_cast<uint2*>(outl + (size_t)node * Dout + jc) = pl;
    } else {
        *reinterpret_cast<float4*>(outf + (size_t)node * Dout + jc) =
            make_float4(res[0], res[1], res[2], res[3]);
    }
}

extern "C" void kernel_launch(void* const* d_in, const int* in_sizes, int n_in,
                              void* d_out, int out_size, void* d_ws, size_t ws_size,
                              hipStream_t stream) {
    const float* x = (const float*)d_in[0];
    const int* src = (const int*)d_in[1];
    const int* dst = (const int*)d_in[2];
    const int Nn = in_sizes[0] / 128;   // 50000
    const int E0 = in_sizes[1];         // 400000
    const int Etot = E0 + Nn;

    // ---- workspace layout (~108 MB, same as round 7) ----
    u16* A0 = (u16*)d_ws;                                  // Nn*512 u16
    u16* Bh = A0 + (size_t)Nn * 512;                       // Nn*256 u16 (GEMM bf16 out, head-major)
    u16* Ch = Bh + (size_t)Nn * 256;                       // Nn*256 u16 (Y2 hi/lo)
    float* es = (float*)(Ch + (size_t)Nn * 256);           // Nn*8 (head-major)
    float* ed = es + (size_t)Nn * 8;                       // Nn*8
    int* row_ptr = (int*)(ed + (size_t)Nn * 8);            // Nn+1
    int* cursor  = row_ptr + (Nn + 1);                     // Nn
    int* col     = cursor + Nn;                            // Etot
    u16* wth = (u16*)(col + Etot);                         // 64K u16
    u16* wtl = wth + 65536;

    u16* XH = A0;
    u16* XL = A0 + (size_t)Nn * 128;
    u16* Y1H = A0;
    u16* Y1L = A0 + (size_t)Nn * 256;
    u16* Y2H = Ch;
    u16* Y2L = Ch + (size_t)Nn * 128;
    float* out3 = (float*)A0;

    // ---- CSR build ----
    hipMemsetAsync(cursor, 0, sizeof(int) * Nn, stream);
    hist_kernel<<<(Etot + 255) / 256, 256, 0, stream>>>(dst, cursor, E0, Etot);
    scan_kernel<<<1, 1024, 0, stream>>>(cursor, row_ptr, Nn);
    hipMemcpyAsync(cursor, row_ptr, sizeof(int) * Nn, hipMemcpyDeviceToDevice, stream);
    scatter_kernel<<<(Etot + 255) / 256, 256, 0, stream>>>(src, dst, cursor, col, E0, Etot);

    const int gy128 = (Nn + 127) / 128;

    for (int l = 0; l < 4; l++) {
        const float* const* p = (const float* const*)(d_in + 3 + l * 8);
        const float* W    = p[0];
        const float* asrc = p[1];
        const float* adst = p[2];
        const float* bias = p[3];
        const float* g    = p[4];
        const float* be   = p[5];
        const float* rm   = p[6];
        const float* rv   = p[7];

        if (l == 0) {
            const int K = 128, N = 256;
            int n4 = Nn * K / 4;
            split_kernel<<<(n4 + 255) / 256, 256, 0, stream>>>(
                (const float4*)x, (uint2*)XH, (uint2*)XL, n4);
            wt_prep<<<(K * N + 255) / 256, 256, 0, stream>>>(W, wth, wtl, K, N);
            gemm_mfma<128, 32><<<dim3(N / 128, gy128), 256, 0, stream>>>(XH, XL, wth, wtl, Bh, Nn, K, N);
            scores_kernel<<<(Nn * 8 + 255) / 256, 256, 0, stream>>>(Bh, asrc, adst, es, ed, Nn, 8, 32);
            gat_fused<8, 32, 8, 1, 1><<<dim3((Nn + 31) / 32, 8), 256, 0, stream>>>(
                row_ptr, col, es, ed, Bh, nullptr, Y1H, Y1L, bias, g, be, rm, rv, Nn);
        } else if (l == 1) {
            const int K = 256, N = 128;
            wt_prep<<<(K * N + 255) / 256, 256, 0, stream>>>(W, wth, wtl, K, N);
            gemm_mfma<128, 16><<<dim3(1, gy128), 256, 0, stream>>>(Y1H, Y1L, wth, wtl, Bh, Nn, K, N);
            scores_kernel<<<(Nn * 8 + 255) / 256, 256, 0, stream>>>(Bh, asrc, adst, es, ed, Nn, 8, 16);
            gat_fused<8, 16, 4, 1, 1><<<dim3((Nn + 63) / 64, 8), 256, 0, stream>>>(
                row_ptr, col, es, ed, Bh, nullptr, Y2H, Y2L, bias, g, be, rm, rv, Nn);
        } else if (l == 2) {
            const int K = 128, N = 64;
            wt_prep<<<(K * N + 255) / 256, 256, 0, stream>>>(W, wth, wtl, K, N);
            gemm_mfma<64, 8><<<dim3(1, gy128), 256, 0, stream>>>(Y2H, Y2L, wth, wtl, Bh, Nn, K, N);
            scores_kernel<<<(Nn * 8 + 255) / 256, 256, 0, stream>>>(Bh, asrc, adst, es, ed, Nn, 8, 8);
            gat_fused<8, 8, 2, 1, 0><<<dim3((Nn + 127) / 128, 8), 256, 0, stream>>>(
                row_ptr, col, es, ed, Bh, out3, nullptr, nullptr, bias, g, be, rm, rv, Nn);
        } else {
            gemm_k64n16<<<(Nn + 63) / 64, 256, 0, stream>>>(out3, W, Bh, Nn);
            scores_kernel<<<(Nn + 255) / 256, 256, 0, stream>>>(Bh, asrc, adst, es, ed, Nn, 1, 16);
            gat_fused<1, 16, 4, 0, 0><<<dim3((Nn + 63) / 64, 1), 256, 0, stream>>>(
                row_ptr, col, es, ed, Bh, (float*)d_out, nullptr, nullptr, bias, g, be, rm, rv, Nn);
        }
    }
}